// Round 1
// baseline (223.801 us; speedup 1.0000x reference)
//
#include <hip/hip_runtime.h>

// Seq2SeqLSTM: H=64, F=8, T=512, P=64, B=1024, fp32 in/out.
// R13 = R12 + critical-path polish (no structural change):
//   (1) qgates: MFMA pairs accumulator-chained g,g,i,i,f,f,o,o so Qg (head of
//       the longest cell dependency) completes earliest.
//   (2) shadow MFMAs (pchain / decoder fc) explicitly issued between the gate
//       MFMAs and the cell VALU -> they fill the Qg-latency gap.
//   (3) cell output reformulated: h = fma(-2*so, rcp(1+e^{2c}), so), so/m2so
//       precomputed off-spine; clamp via v_med3_f32.
//   (4) h-write bank-conflict fix: writers q>=2 XOR k-offset by 16 halves,
//       readers with col>=8 use q^2 -> 64x2B write hits all 32 banks.
// Topology: MB=4 over 256 blocks; lane (q,col) owns cell (batch q, unit
// wv*16+col); batch b at A-row 4b so C/D row=4q+0 puts gates in acc[.][0];
// fp16 weights/h/x pre-scaled by log2e (2*log2e for g-gate); fused-rcp cell.

#define Hh 64
#define Ff 8
#define Tt 512
#define Pp 64
#define BATCH 1024
#define MB 4
#define NBLK (BATCH / MB)   // 256 blocks
#define ROWS 72             // halves per A row (64 + 8 pad)
#define ABUF (16 * ROWS + 64)
#define XSTRIDE 32          // halves per x step-row: 4 batches * 8

typedef __attribute__((ext_vector_type(8))) _Float16 half8;
typedef __attribute__((ext_vector_type(4))) _Float16 half4;
typedef __attribute__((ext_vector_type(4))) float f32x4;

#define LOG2E  1.44269504088896340736f
#define K2LOG2 2.88538008177792681472f   // 2*log2e

__device__ __forceinline__ float rcp_(float x)  { return __builtin_amdgcn_rcpf(x); }
__device__ __forceinline__ float exp2_(float x) { return __builtin_amdgcn_exp2f(x); }
// A-row swizzle (halves): rows 4b (writers) keep offset 0.
__device__ __forceinline__ int arow_base(int m) { return m * ROWS + (m & 3) * 16; }

// B-fragments: 4 gate tiles, fp16, log2e-pre-scaled (2*log2e for g-gate).
// B layout (16x16x32): lane holds B[k = kc*32 + q*8 + j][n = col].
__device__ __forceinline__ void load_wfrags(
    const float* __restrict__ Whh, const float* __restrict__ Wih,
    int wv, int q, int col, half8 w0[4], half8 w1[4], half8 wx[4])
{
    #pragma unroll
    for (int Tg = 0; Tg < 4; ++Tg) {
        int g = Tg * 64 + wv * 16 + col;
        float sc = (Tg == 2) ? K2LOG2 : LOG2E;
        const float* r0 = Whh + g * 64 + q * 8;
        #pragma unroll
        for (int j = 0; j < 8; ++j) {
            w0[Tg][j] = (_Float16)(r0[j] * sc);
            w1[Tg][j] = (_Float16)(r0[32 + j] * sc);
            wx[Tg][j] = (q == 0) ? (_Float16)(Wih[g * 8 + j] * sc) : (_Float16)0.f;
        }
    }
}

// P[Tg] = x-contribution + bias (C-init). Off the critical path.
__device__ __forceinline__ void pchain(half8 ax, const half8 wx[4],
                                       const f32x4 biasv[4], f32x4 P[4])
{
    P[2] = __builtin_amdgcn_mfma_f32_16x16x32_f16(ax, wx[2], biasv[2], 0, 0, 0);
    P[0] = __builtin_amdgcn_mfma_f32_16x16x32_f16(ax, wx[0], biasv[0], 0, 0, 0);
    P[1] = __builtin_amdgcn_mfma_f32_16x16x32_f16(ax, wx[1], biasv[1], 0, 0, 0);
    P[3] = __builtin_amdgcn_mfma_f32_16x16x32_f16(ax, wx[3], biasv[3], 0, 0, 0);
}

// Gate MFMAs: accumulator-chained pairs, g-gate first (longest downstream dep).
__device__ __forceinline__ void qgates(half8 a0, half8 a1,
    const half8 w0[4], const half8 w1[4], const f32x4 P[4], f32x4 Q[4])
{
    Q[2] = __builtin_amdgcn_mfma_f32_16x16x32_f16(a0, w0[2], P[2], 0, 0, 0);
    Q[2] = __builtin_amdgcn_mfma_f32_16x16x32_f16(a1, w1[2], Q[2], 0, 0, 0);
    Q[0] = __builtin_amdgcn_mfma_f32_16x16x32_f16(a0, w0[0], P[0], 0, 0, 0);
    Q[0] = __builtin_amdgcn_mfma_f32_16x16x32_f16(a1, w1[0], Q[0], 0, 0, 0);
    Q[1] = __builtin_amdgcn_mfma_f32_16x16x32_f16(a0, w0[1], P[1], 0, 0, 0);
    Q[1] = __builtin_amdgcn_mfma_f32_16x16x32_f16(a1, w1[1], Q[1], 0, 0, 0);
    Q[3] = __builtin_amdgcn_mfma_f32_16x16x32_f16(a0, w0[3], P[3], 0, 0, 0);
    Q[3] = __builtin_amdgcn_mfma_f32_16x16x32_f16(a1, w1[3], Q[3], 0, 0, 0);
}

// Fused-rcp cell. Spine: eg -> it -> cS fma -> med3 -> ec -> rc -> fma -> cvt.
__device__ __forceinline__ float cellf(const f32x4 Q[4], float& cS)
{
    float eg = exp2_(Q[2][0]);            // e^{2g} (g-row pre-scaled 2*log2e)
    float ei = exp2_(-Q[0][0]);
    float it = (eg - 1.f) * rcp_((1.f + ei) * (1.f + eg));   // si*tanh(g)
    float ef = exp2_(-Q[1][0]);
    float sf = rcp_(1.f + ef);
    float eo = exp2_(-Q[3][0]);
    float so   = rcp_(1.f + eo);          // sigmoid(o), off-spine
    float m2so = -2.f * so;
    cS = __builtin_fmaf(sf, cS, K2LOG2 * it);                // cS = 2*log2e*c
    float cc = __builtin_amdgcn_fmed3f(cS, -60.f, 60.f);     // exp2 guard
    float ec = exp2_(cc);                                    // e^{2c}
    float rc = rcp_(1.f + ec);
    return __builtin_fmaf(m2so, rc, so);  // so*tanh(c) = so*(1 - 2/(1+e^{2c}))
}

__global__ __launch_bounds__(256, 1)
void seq2seq_v13(const float* __restrict__ x_seq,
                 const float* __restrict__ eWih, const float* __restrict__ eWhh,
                 const float* __restrict__ ebih, const float* __restrict__ ebhh,
                 const float* __restrict__ dWih, const float* __restrict__ dWhh,
                 const float* __restrict__ dbih, const float* __restrict__ dbhh,
                 const float* __restrict__ fcW,  const float* __restrict__ fcb,
                 float* __restrict__ out)
{
    __shared__ __align__(16) _Float16 xs[(Tt + 2) * XSTRIDE];  // 32.9 KB; predbuf alias
    __shared__ __align__(16) _Float16 A0[ABUF];
    __shared__ __align__(16) _Float16 A1[ABUF];

    const int tid  = threadIdx.x;
    const int wv   = tid >> 6;
    const int lane = tid & 63;
    const int q    = lane >> 4;
    const int col  = lane & 15;
    const int u    = wv * 16 + col;
    const int b0   = blockIdx.x * MB;

    half8 w0[4], w1[4], wx[4];
    load_wfrags(eWhh, eWih, wv, q, col, w0, w1, wx);
    f32x4 biasv[4];
    #pragma unroll
    for (int Tg = 0; Tg < 4; ++Tg) {
        int g = Tg * 64 + u;
        float sc = (Tg == 2) ? K2LOG2 : LOG2E;
        float bv = (ebih[g] + ebhh[g]) * sc;
        biasv[Tg] = (f32x4){bv, bv, bv, bv};
    }

    // init: zero A buffers + xs pad rows, stage x (fp32 -> fp16)
    { int* Z0 = (int*)A0; int* Z1 = (int*)A1;
      for (int i = tid; i < ABUF / 2; i += 256) { Z0[i] = 0; Z1[i] = 0; } }
    if (tid < 32) ((int*)xs)[Tt * 16 + tid] = 0;         // zero 2 pad rows
    for (int i = tid; i < MB * Tt * 2; i += 256) {       // 4096 float4s
        int b   = i >> 10;
        int rem = i & 1023;
        int t   = rem >> 1;
        int f4  = (rem & 1) * 4;
        const float* src = x_seq + ((size_t)(b0 + b) * Tt + t) * Ff + f4;
        half4 s = { (_Float16)src[0], (_Float16)src[1], (_Float16)src[2], (_Float16)src[3] };
        *(half4*)(&xs[t * XSTRIDE + b * 8 + f4]) = s;
    }
    __syncthreads();                                     // staging visible

    // per-lane hoisted pointers.
    // Read swizzle: rows (=col) >= 8 store k-groups XOR'd by 16 halves.
    // Write swizzle: writers q>=2 XOR their k-offset by 16 -> conflict-free
    // 64x2B h-write (all 32 banks, <=2 lanes/bank same-dword).
    const int qr = (col & 8) ? (q ^ 2) : q;
    const _Float16* arA = A0 + arow_base(col) + qr * 8;
    const _Float16* arB = A1 + arow_base(col) + qr * 8;
    const int uw = u ^ ((q & 2) << 3);
    _Float16* hwA = A0 + 4 * q * ROWS + uw;
    _Float16* hwB = A1 + 4 * q * ROWS + uw;
    const _Float16* xq = xs + (col >> 2) * 8;            // x walker (broadcast groups)

    float cS = 0.f;
    f32x4 P[4];
    {   half8 ax = *(const half8*)(xq);                  // x(0)
        pchain(ax, wx, biasv, P);                        // P for step 0
        xq += XSTRIDE; }

    // ============ encoder: 512 steps, barrier at top, P one step ahead ============
    for (int t = 0; t < Tt; t += 2) {
        __syncthreads();                                 // h(t) visible (A0)
        {
            half8 a0 = *(const half8*)(arA);
            half8 a1 = *(const half8*)(arA + 32);
            half8 ax = *(const half8*)(xq); xq += XSTRIDE;   // x(t+1), off-CP
            f32x4 Q[4];
            qgates(a0, a1, w0, w1, P, Q);
            pchain(ax, wx, biasv, P);                    // fills Qg-latency gap
            float hn = cellf(Q, cS);
            *hwB = (_Float16)hn;                         // h(t+1) -> A1
        }
        __syncthreads();                                 // h(t+1) visible (A1)
        {
            half8 a0 = *(const half8*)(arB);
            half8 a1 = *(const half8*)(arB + 32);
            half8 ax = *(const half8*)(xq); xq += XSTRIDE;   // x(t+2) (pad rows at end)
            f32x4 Q[4];
            qgates(a0, a1, w0, w1, P, Q);
            pchain(ax, wx, biasv, P);
            float hn = cellf(Q, cS);
            *hwA = (_Float16)hn;                         // h(t+2) -> A0
        }
    }
    // after loop: H_0 (encoder final h) in A0.

    // ================= decoder setup =================
    half8 axl = *(const half8*)(xs + (Tt - 1) * XSTRIDE + (col >> 2) * 8);

    // Plain decoder weights (step 0 only) + folded weights W' (steps 1..63).
    half8 wp0[4], wp1[4];
    f32x4 biasp[4];
    #pragma unroll
    for (int Tg = 0; Tg < 4; ++Tg) {
        int g = Tg * 64 + u;
        float sc = (Tg == 2) ? K2LOG2 : LOG2E;
        #pragma unroll
        for (int j = 0; j < 8; ++j) {
            int k0 = q * 8 + j;
            float v0 = dWhh[g * 64 + k0];
            float v1 = dWhh[g * 64 + 32 + k0];
            w0[Tg][j] = (_Float16)(v0 * sc);             // plain (step 0)
            w1[Tg][j] = (_Float16)(v1 * sc);
            wx[Tg][j] = (q == 0) ? (_Float16)(dWih[g * 8 + j] * sc) : (_Float16)0.f;
            float s0 = v0, s1 = v1;                      // fold: W' = Whh + Wih*fcW
            #pragma unroll
            for (int f = 0; f < 8; ++f) {
                float wif = dWih[g * 8 + f];
                s0 = __builtin_fmaf(wif, fcW[f * 64 + k0], s0);
                s1 = __builtin_fmaf(wif, fcW[f * 64 + 32 + k0], s1);
            }
            wp0[Tg][j] = (_Float16)(s0 * sc);
            wp1[Tg][j] = (_Float16)(s1 * sc);
        }
        float bb = dbih[g] + dbhh[g];
        float bp = bb;                                   // b' = b + Wih*fcb
        #pragma unroll
        for (int f = 0; f < 8; ++f) bp = __builtin_fmaf(dWih[g * 8 + f], fcb[f], bp);
        biasv[Tg] = (f32x4){bb * sc, bb * sc, bb * sc, bb * sc};
        biasp[Tg] = (f32x4){bp * sc, bp * sc, bp * sc, bp * sc};
    }
    // fc fragments: pred[b][f] = sum_u h[b][u]*fcW[f][u] + fcb[f]
    half8 wf0, wf1;
    f32x4 biasf;
    {
        #pragma unroll
        for (int j = 0; j < 8; ++j) {
            wf0[j] = (col < 8) ? (_Float16)fcW[col * 64 + q * 8 + j]      : (_Float16)0.f;
            wf1[j] = (col < 8) ? (_Float16)fcW[col * 64 + 32 + q * 8 + j] : (_Float16)0.f;
        }
        float fb = (col < 8) ? fcb[col] : 0.f;
        biasf = (f32x4){fb, fb, fb, fb};
    }

    float* predbuf = (float*)xs;                         // 8 KB alias over dead xs
    const bool pw = (wv == 0) && (col < 8);              // pred writer lanes

    // ---- decoder step 0: plain path, x = x_last; pchain hoisted off-CP ----
    pchain(axl, wx, biasv, P);
    __syncthreads();                                     // H_0 visible (A0)
    {
        half8 a0 = *(const half8*)(arA);
        half8 a1 = *(const half8*)(arA + 32);
        f32x4 Q[4];
        qgates(a0, a1, w0, w1, P, Q);
        float hn = cellf(Q, cS);
        *hwB = (_Float16)hn;                             // H_1 -> A1
    }

    // ---- decoder steps 1..63: pure h-recurrence (folded W'), pred in shadow ----
    for (int p = 1; p < Pp; ++p) {
        __syncthreads();                                 // H_p visible
        const _Float16* ar = (p & 1) ? arB : arA;
        _Float16*       hw = (p & 1) ? hwA : hwB;
        half8 a0 = *(const half8*)(ar);
        half8 a1 = *(const half8*)(ar + 32);
        f32x4 Q[4];
        qgates(a0, a1, wp0, wp1, biasp, Q);              // CP: same as encoder
        // shadow: pred(p-1) = fc(H_p), issued into the Qg-latency gap
        f32x4 F = __builtin_amdgcn_mfma_f32_16x16x32_f16(a0, wf0, biasf, 0, 0, 0);
        F       = __builtin_amdgcn_mfma_f32_16x16x32_f16(a1, wf1, F,     0, 0, 0);
        float hn = cellf(Q, cS);
        *hw = (_Float16)hn;                              // H_{p+1}
        if (pw) predbuf[q * (Pp * Ff) + (p - 1) * Ff + col] = F[0];
    }

    // ---- epilogue: pred(63) = fc(H_64) (H_64 in A0: p=63 odd wrote hwA) ----
    __syncthreads();
    {
        half8 a0 = *(const half8*)(arA);
        half8 a1 = *(const half8*)(arA + 32);
        f32x4 F = __builtin_amdgcn_mfma_f32_16x16x32_f16(a0, wf0, biasf, 0, 0, 0);
        F       = __builtin_amdgcn_mfma_f32_16x16x32_f16(a1, wf1, F,     0, 0, 0);
        if (pw) predbuf[q * (Pp * Ff) + (Pp - 1) * Ff + col] = F[0];
    }
    __syncthreads();

    // ================= flush preds: LDS -> global, coalesced float4 =================
    {
        f32x4* out4 = (f32x4*)out + (size_t)b0 * (Pp * Ff / 4);
        const f32x4* pb4 = (const f32x4*)predbuf;
        for (int i = tid; i < MB * Pp * Ff / 4; i += 256)
            out4[i] = pb4[i];
    }
}

extern "C" void kernel_launch(void* const* d_in, const int* in_sizes, int n_in,
                              void* d_out, int out_size, void* d_ws, size_t ws_size,
                              hipStream_t stream) {
    (void)in_sizes; (void)n_in; (void)d_ws; (void)ws_size; (void)out_size;
    hipLaunchKernelGGL(seq2seq_v13, dim3(NBLK), dim3(256), 0, stream,
                       (const float*)d_in[0],
                       (const float*)d_in[1], (const float*)d_in[2],
                       (const float*)d_in[3], (const float*)d_in[4],
                       (const float*)d_in[5], (const float*)d_in[6],
                       (const float*)d_in[7], (const float*)d_in[8],
                       (const float*)d_in[9], (const float*)d_in[10],
                       (float*)d_out);
}